// Round 1
// baseline (180764.478 us; speedup 1.0000x reference)
//
#include <hip/hip_runtime.h>
#include <hip/hip_bf16.h>

#define NWG 256   // persistent workgroups == #CUs; each owns 4 hidden units
#define NTH 256   // 4 waves: wave w computes gate w (i,f,g,o) for the WG's 4 units
#define T1  8192  // S*W word steps
#define SS  64
#define WW  128

// ws layout (4B units): [0..255] flags, [256..511] partials,
// [512..2559] hbuf (2 x 1024), [2560..68095] encs (64 x 1024)  => 272 KB

__global__ __launch_bounds__(NTH, 1)
void lstm_hier_attn(const float* __restrict__ xin,
                    const float* __restrict__ h1_0, const float* __restrict__ c1_0,
                    const float* __restrict__ h2_0, const float* __restrict__ c2_0,
                    const float* __restrict__ Wih1, const float* __restrict__ Whh1,
                    const float* __restrict__ bih1, const float* __restrict__ bhh1,
                    const float* __restrict__ Wih2, const float* __restrict__ Whh2,
                    const float* __restrict__ bih2, const float* __restrict__ bhh2,
                    const float* __restrict__ attw, const float* __restrict__ atts,
                    const float* __restrict__ Wf,   const float* __restrict__ bfb,
                    int* flags, float* partials, float* hbuf, float* encs,
                    float* out)
{
  const int wid = blockIdx.x;
  const int tid = threadIdx.x;
  const int wv  = tid >> 6;   // wave id == gate index (i,f,g,o)
  const int l   = tid & 63;   // lane
  const int u0  = wid << 2;   // first hidden unit owned by this WG

  __shared__ float h_lds[1024];
  __shared__ float aw_lds[WW];
  __shared__ float as_lds[SS];
  __shared__ float g_lds[16];
  __shared__ float c_lds[4];
  __shared__ float enc_lds[4];
  __shared__ float row_lds[4];

  // one-time: softmaxes (serial by t0 — one-time cost ~1-2us, overlapped with weight load)
  if (tid == 0) {
    float m = -1e30f;
    for (int i = 0; i < WW; ++i) m = fmaxf(m, attw[i]);
    float ssum = 0.f;
    for (int i = 0; i < WW; ++i) { float e = __expf(attw[i] - m); aw_lds[i] = e; ssum += e; }
    float inv = 1.f / ssum;
    for (int i = 0; i < WW; ++i) aw_lds[i] *= inv;
    m = -1e30f;
    for (int i = 0; i < SS; ++i) m = fmaxf(m, atts[i]);
    ssum = 0.f;
    for (int i = 0; i < SS; ++i) { float e = __expf(atts[i] - m); as_lds[i] = e; ssum += e; }
    inv = 1.f / ssum;
    for (int i = 0; i < SS; ++i) as_lds[i] *= inv;
  }
  if (tid < 4) {
    c_lds[tid]   = c1_0[u0 + tid];
    enc_lds[tid] = 0.f;
    row_lds[tid] = 0.f;
  }

  // layer-1 weights resident in VGPRs: thread (wv,l) holds rows (wv*1024+u0+i),
  // columns jj*64+l  (lane-interleaved => coalesced global loads, conflict-free LDS h reads)
  float wih[4][16], whh[4][16], bias[4];
#pragma unroll
  for (int i = 0; i < 4; ++i) {
    const int row = (wv << 10) + u0 + i;
    bias[i] = bih1[row] + bhh1[row];
    const float* pih = Wih1 + (size_t)row * 1024 + l;
    const float* phh = Whh1 + (size_t)row * 1024 + l;
#pragma unroll
    for (int jj = 0; jj < 16; ++jj) {
      wih[i][jj] = pih[jj * 64];
      whh[i][jj] = phh[jj * 64];
    }
  }
  __syncthreads();

  float* buf0 = hbuf;
  float* buf1 = hbuf + 1024;

  // ======================= layer 1: 8192 word steps =======================
  for (int s = 0; s < T1; ++s) {
    // x-part first: independent of h, hides under the flag wait
    const float* xrow = xin + (size_t)s * 1024 + l;
    float xa0 = 0.f, xa1 = 0.f, xa2 = 0.f, xa3 = 0.f;
#pragma unroll
    for (int jj = 0; jj < 16; ++jj) {
      const float xv = xrow[jj * 64];
      xa0 += wih[0][jj] * xv; xa1 += wih[1][jj] * xv;
      xa2 += wih[2][jj] * xv; xa3 += wih[3][jj] * xv;
    }
    // wait for h_s, then stage it to LDS (agent-scope loads bypass non-coherent L2s)
    if (s > 0) {
      int v;
      do { v = __hip_atomic_load(&flags[tid], __ATOMIC_ACQUIRE, __HIP_MEMORY_SCOPE_AGENT); }
      while (__syncthreads_count(v >= s) < NTH);
      float* src = (s & 1) ? buf1 : buf0;
#pragma unroll
      for (int q = 0; q < 4; ++q) {
        const int c = (q << 8) + tid;
        h_lds[c] = __hip_atomic_load(&src[c], __ATOMIC_RELAXED, __HIP_MEMORY_SCOPE_AGENT);
      }
    } else {
#pragma unroll
      for (int q = 0; q < 4; ++q) { const int c = (q << 8) + tid; h_lds[c] = h1_0[c]; }
    }
    __syncthreads();
    // h-GEMV (weights in VGPRs; h_lds reads are 2-way-bank = free)
    float ha0 = 0.f, ha1 = 0.f, ha2 = 0.f, ha3 = 0.f;
#pragma unroll
    for (int jj = 0; jj < 16; ++jj) {
      const float hv = h_lds[jj * 64 + l];
      ha0 += whh[0][jj] * hv; ha1 += whh[1][jj] * hv;
      ha2 += whh[2][jj] * hv; ha3 += whh[3][jj] * hv;
    }
    float g0 = xa0 + ha0, g1 = xa1 + ha1, g2 = xa2 + ha2, g3 = xa3 + ha3;
#pragma unroll
    for (int m = 1; m < 64; m <<= 1) {
      g0 += __shfl_xor(g0, m); g1 += __shfl_xor(g1, m);
      g2 += __shfl_xor(g2, m); g3 += __shfl_xor(g3, m);
    }
    if (l == 0) {
      g_lds[(wv << 2) + 0] = g0 + bias[0];
      g_lds[(wv << 2) + 1] = g1 + bias[1];
      g_lds[(wv << 2) + 2] = g2 + bias[2];
      g_lds[(wv << 2) + 3] = g3 + bias[3];
    }
    __syncthreads();
    if (tid < 4) {                       // torch gate order: i,f,g,o
      const int j = tid;
      const float ig = g_lds[0 + j], fg = g_lds[4 + j], gg = g_lds[8 + j], og = g_lds[12 + j];
      const float si = 1.f / (1.f + __expf(-ig));
      const float sf = 1.f / (1.f + __expf(-fg));
      const float so = 1.f / (1.f + __expf(-og));
      const float c  = sf * c_lds[j] + si * tanhf(gg);
      const float h  = so * tanhf(c);
      c_lds[j] = c;
      const int wd = s & (WW - 1);
      float e = enc_lds[j] + aw_lds[wd] * h;          // enc = aw @ hs (online)
      float* dst = ((s + 1) & 1) ? buf1 : buf0;
      __hip_atomic_store(&dst[u0 + j], h, __ATOMIC_RELAXED, __HIP_MEMORY_SCOPE_AGENT);
      if (wd == WW - 1) {
        __hip_atomic_store(&encs[(s >> 7) * 1024 + u0 + j], e,
                           __ATOMIC_RELAXED, __HIP_MEMORY_SCOPE_AGENT);
        e = 0.f;
      }
      enc_lds[j] = e;
    }
    __syncthreads();
    if (tid == 0)
      __hip_atomic_store(&flags[wid], s + 1, __ATOMIC_RELEASE, __HIP_MEMORY_SCOPE_AGENT);
  }

  // ======================= layer 2: 64 sentence steps =======================
#pragma unroll
  for (int i = 0; i < 4; ++i) {          // reuse the same VGPRs for layer-2 weights
    const int row = (wv << 10) + u0 + i;
    bias[i] = bih2[row] + bhh2[row];
    const float* pih = Wih2 + (size_t)row * 1024 + l;
    const float* phh = Whh2 + (size_t)row * 1024 + l;
#pragma unroll
    for (int jj = 0; jj < 16; ++jj) {
      wih[i][jj] = pih[jj * 64];
      whh[i][jj] = phh[jj * 64];
    }
  }
  if (tid < 4) c_lds[tid] = c2_0[u0 + tid];

  for (int s2 = 0; s2 < SS; ++s2) {
    const int sg = T1 + s2;
    float* erow = encs + (size_t)s2 * 1024 + l;
    float xa0 = 0.f, xa1 = 0.f, xa2 = 0.f, xa3 = 0.f;
#pragma unroll
    for (int jj = 0; jj < 16; ++jj) {
      const float ev = __hip_atomic_load(&erow[jj * 64], __ATOMIC_RELAXED, __HIP_MEMORY_SCOPE_AGENT);
      xa0 += wih[0][jj] * ev; xa1 += wih[1][jj] * ev;
      xa2 += wih[2][jj] * ev; xa3 += wih[3][jj] * ev;
    }
    {
      int v;
      do { v = __hip_atomic_load(&flags[tid], __ATOMIC_ACQUIRE, __HIP_MEMORY_SCOPE_AGENT); }
      while (__syncthreads_count(v >= sg) < NTH);
    }
    if (s2 == 0) {
#pragma unroll
      for (int q = 0; q < 4; ++q) { const int c = (q << 8) + tid; h_lds[c] = h2_0[c]; }
    } else {
      float* src = (sg & 1) ? buf1 : buf0;
#pragma unroll
      for (int q = 0; q < 4; ++q) {
        const int c = (q << 8) + tid;
        h_lds[c] = __hip_atomic_load(&src[c], __ATOMIC_RELAXED, __HIP_MEMORY_SCOPE_AGENT);
      }
    }
    __syncthreads();
    float ha0 = 0.f, ha1 = 0.f, ha2 = 0.f, ha3 = 0.f;
#pragma unroll
    for (int jj = 0; jj < 16; ++jj) {
      const float hv = h_lds[jj * 64 + l];
      ha0 += whh[0][jj] * hv; ha1 += whh[1][jj] * hv;
      ha2 += whh[2][jj] * hv; ha3 += whh[3][jj] * hv;
    }
    float g0 = xa0 + ha0, g1 = xa1 + ha1, g2 = xa2 + ha2, g3 = xa3 + ha3;
#pragma unroll
    for (int m = 1; m < 64; m <<= 1) {
      g0 += __shfl_xor(g0, m); g1 += __shfl_xor(g1, m);
      g2 += __shfl_xor(g2, m); g3 += __shfl_xor(g3, m);
    }
    if (l == 0) {
      g_lds[(wv << 2) + 0] = g0 + bias[0];
      g_lds[(wv << 2) + 1] = g1 + bias[1];
      g_lds[(wv << 2) + 2] = g2 + bias[2];
      g_lds[(wv << 2) + 3] = g3 + bias[3];
    }
    __syncthreads();
    if (tid < 4) {
      const int j = tid;
      const float ig = g_lds[0 + j], fg = g_lds[4 + j], gg = g_lds[8 + j], og = g_lds[12 + j];
      const float si = 1.f / (1.f + __expf(-ig));
      const float sf = 1.f / (1.f + __expf(-fg));
      const float so = 1.f / (1.f + __expf(-og));
      const float c  = sf * c_lds[j] + si * tanhf(gg);
      const float h  = so * tanhf(c);
      c_lds[j] = c;
      row_lds[j] += as_lds[s2] * h;                    // row = asn @ hs2 (online)
      float* dst = ((sg + 1) & 1) ? buf1 : buf0;
      __hip_atomic_store(&dst[u0 + j], h, __ATOMIC_RELAXED, __HIP_MEMORY_SCOPE_AGENT);
    }
    __syncthreads();
    if (tid == 0)
      __hip_atomic_store(&flags[wid], sg + 1, __ATOMIC_RELEASE, __HIP_MEMORY_SCOPE_AGENT);
  }

  // =================== final projection + sigmoid ===================
  if (tid == 0) {
    const float p = row_lds[0] * Wf[u0 + 0] + row_lds[1] * Wf[u0 + 1]
                  + row_lds[2] * Wf[u0 + 2] + row_lds[3] * Wf[u0 + 3];
    __hip_atomic_store(&partials[wid], p, __ATOMIC_RELAXED, __HIP_MEMORY_SCOPE_AGENT);
    __hip_atomic_store(&flags[wid], T1 + SS + 1, __ATOMIC_RELEASE, __HIP_MEMORY_SCOPE_AGENT);
  }
  if (wid == 0) {
    int v;
    do { v = __hip_atomic_load(&flags[tid], __ATOMIC_ACQUIRE, __HIP_MEMORY_SCOPE_AGENT); }
    while (__syncthreads_count(v >= T1 + SS + 1) < NTH);
    float p = __hip_atomic_load(&partials[tid], __ATOMIC_RELAXED, __HIP_MEMORY_SCOPE_AGENT);
#pragma unroll
    for (int m = 1; m < 64; m <<= 1) p += __shfl_xor(p, m);
    if (l == 0) g_lds[wv] = p;
    __syncthreads();
    if (tid == 0)
      out[0] = 1.f / (1.f + __expf(-(g_lds[0] + g_lds[1] + g_lds[2] + g_lds[3] + bfb[0])));
  }
}

extern "C" void kernel_launch(void* const* d_in, const int* in_sizes, int n_in,
                              void* d_out, int out_size, void* d_ws, size_t ws_size,
                              hipStream_t stream) {
  (void)in_sizes; (void)n_in; (void)out_size; (void)ws_size;
  const float* xin  = (const float*)d_in[0];
  const float* h1   = (const float*)d_in[1];
  const float* c1   = (const float*)d_in[2];
  const float* h2   = (const float*)d_in[3];
  const float* c2   = (const float*)d_in[4];
  const float* Wih1 = (const float*)d_in[5];
  const float* Whh1 = (const float*)d_in[6];
  const float* bih1 = (const float*)d_in[7];
  const float* bhh1 = (const float*)d_in[8];
  const float* Wih2 = (const float*)d_in[9];
  const float* Whh2 = (const float*)d_in[10];
  const float* bih2 = (const float*)d_in[11];
  const float* bhh2 = (const float*)d_in[12];
  const float* attw = (const float*)d_in[13];
  const float* atts = (const float*)d_in[14];
  const float* Wf   = (const float*)d_in[15];
  const float* bfb  = (const float*)d_in[16];

  int*   flags    = (int*)d_ws;
  float* partials = (float*)d_ws + 256;
  float* hbuf     = (float*)d_ws + 512;
  float* encs     = (float*)d_ws + 2560;
  float* out      = (float*)d_out;

  // flags must start at 0 every call (replay-safe; graph-capture legal)
  hipMemsetAsync(flags, 0, NWG * sizeof(int), stream);
  lstm_hier_attn<<<dim3(NWG), dim3(NTH), 0, stream>>>(
      xin, h1, c1, h2, c2, Wih1, Whh1, bih1, bhh1,
      Wih2, Whh2, bih2, bhh2, attw, atts, Wf, bfb,
      flags, partials, hbuf, encs, out);
}

// Round 2
// 20730.035 us; speedup vs baseline: 8.7199x; 8.7199x over previous
//
#include <hip/hip_runtime.h>
#include <hip/hip_bf16.h>

#define NWG 256   // persistent workgroups == #CUs; each owns 4 hidden units
#define NTH 256   // 4 waves: wave w computes gate w (i,f,g,o) for the WG's 4 units
#define T1  8192  // S*W word steps
#define SS  64
#define WW  128

typedef unsigned long long u64;

// ws layout (8B units): [0..2047] hbuf64 (2 slots x 1024 tagged h),
// [2048..67583] encs64 (64 x 1024 tagged), [67584..67839] part64 (256 tagged)
// total 543872 B, memset to 0 each call (tag 0 == invalid; valid tags start at 1)

__device__ __forceinline__ u64 aload(const u64* p) {
  return __hip_atomic_load(p, __ATOMIC_RELAXED, __HIP_MEMORY_SCOPE_AGENT);
}
__device__ __forceinline__ void astore(u64* p, u64 v) {
  __hip_atomic_store(p, v, __ATOMIC_RELAXED, __HIP_MEMORY_SCOPE_AGENT);
}
__device__ __forceinline__ u64 pack(float v, unsigned tag) {
  return ((u64)tag << 32) | (u64)__float_as_uint(v);
}

// spin until all 4 owned columns (q*256+tid) carry TAG, then deposit to DST lds
#define SPIN_STAGE(SRCP, TAG, DST) do {                                   \
    const u64* _p = (SRCP); const unsigned _t = (TAG); u64 _a, _b, _c, _d;\
    for (;;) {                                                            \
      _a = aload(_p + tid);        _b = aload(_p + 256 + tid);            \
      _c = aload(_p + 512 + tid);  _d = aload(_p + 768 + tid);            \
      if ((((unsigned)(_a >> 32)) == _t) && (((unsigned)(_b >> 32)) == _t)\
       && (((unsigned)(_c >> 32)) == _t) && (((unsigned)(_d >> 32)) == _t)) break; \
    }                                                                     \
    (DST)[tid]       = __uint_as_float((unsigned)_a);                     \
    (DST)[256 + tid] = __uint_as_float((unsigned)_b);                     \
    (DST)[512 + tid] = __uint_as_float((unsigned)_c);                     \
    (DST)[768 + tid] = __uint_as_float((unsigned)_d);                     \
  } while (0)

__global__ __launch_bounds__(NTH, 1)
void lstm_hier_attn(const float* __restrict__ xin,
                    const float* __restrict__ h1_0, const float* __restrict__ c1_0,
                    const float* __restrict__ h2_0, const float* __restrict__ c2_0,
                    const float* __restrict__ Wih1, const float* __restrict__ Whh1,
                    const float* __restrict__ bih1, const float* __restrict__ bhh1,
                    const float* __restrict__ Wih2, const float* __restrict__ Whh2,
                    const float* __restrict__ bih2, const float* __restrict__ bhh2,
                    const float* __restrict__ attw, const float* __restrict__ atts,
                    const float* __restrict__ Wf,   const float* __restrict__ bfb,
                    u64* hbuf64, u64* encs64, u64* part64, float* out)
{
  const int wid = blockIdx.x;
  const int tid = threadIdx.x;
  const int wv  = tid >> 6;   // wave id == gate index (i,f,g,o)
  const int l   = tid & 63;   // lane
  const int u0  = wid << 2;   // first hidden unit owned by this WG

  __shared__ float h_lds[1024];
  __shared__ float e_lds[1024];
  __shared__ float aw_lds[WW];
  __shared__ float as_lds[SS];
  __shared__ float g_lds[16];
  __shared__ float c_lds[4];
  __shared__ float enc_lds[4];
  __shared__ float row_lds[4];

  if (tid == 0) {   // one-time softmaxes (overlaps other WGs' weight loads)
    float m = -1e30f;
    for (int i = 0; i < WW; ++i) m = fmaxf(m, attw[i]);
    float ssum = 0.f;
    for (int i = 0; i < WW; ++i) { float e = __expf(attw[i] - m); aw_lds[i] = e; ssum += e; }
    float inv = 1.f / ssum;
    for (int i = 0; i < WW; ++i) aw_lds[i] *= inv;
    m = -1e30f;
    for (int i = 0; i < SS; ++i) m = fmaxf(m, atts[i]);
    ssum = 0.f;
    for (int i = 0; i < SS; ++i) { float e = __expf(atts[i] - m); as_lds[i] = e; ssum += e; }
    inv = 1.f / ssum;
    for (int i = 0; i < SS; ++i) as_lds[i] *= inv;
  }
  if (tid < 4) {
    c_lds[tid]   = c1_0[u0 + tid];
    enc_lds[tid] = 0.f;
    row_lds[tid] = 0.f;
  }

  // layer-1 weights resident in VGPRs; asm pin prevents re-load/remat per step
  float wih[4][16], whh[4][16], bias[4];
#pragma unroll
  for (int i = 0; i < 4; ++i) {
    const int row = (wv << 10) + u0 + i;
    bias[i] = bih1[row] + bhh1[row];
    const float* pih = Wih1 + (size_t)row * 1024 + l;
    const float* phh = Whh1 + (size_t)row * 1024 + l;
#pragma unroll
    for (int jj = 0; jj < 16; ++jj) {
      wih[i][jj] = pih[jj * 64];
      whh[i][jj] = phh[jj * 64];
    }
  }
#pragma unroll
  for (int i = 0; i < 4; ++i)
#pragma unroll
    for (int jj = 0; jj < 16; ++jj) {
      asm volatile("" : "+v"(wih[i][jj]));
      asm volatile("" : "+v"(whh[i][jj]));
    }
  __syncthreads();

  // ======================= layer 1: 8192 word steps =======================
  for (int s = 0; s < T1; ++s) {
    // issue x-row loads early; FMAs consumed after the spin
    const float* xrow = xin + (size_t)s * 1024 + l;
    float xv[16];
#pragma unroll
    for (int jj = 0; jj < 16; ++jj) xv[jj] = xrow[jj * 64];

    if (s > 0) {
      const u64* src = hbuf64 + ((size_t)(s & 1) << 10);
      SPIN_STAGE(src, (unsigned)s, h_lds);
    } else {
#pragma unroll
      for (int q = 0; q < 4; ++q) h_lds[(q << 8) + tid] = h1_0[(q << 8) + tid];
    }
    __syncthreads();

    float xa0 = 0.f, xa1 = 0.f, xa2 = 0.f, xa3 = 0.f;
    float ha0 = 0.f, ha1 = 0.f, ha2 = 0.f, ha3 = 0.f;
#pragma unroll
    for (int jj = 0; jj < 16; ++jj) {
      const float xvj = xv[jj];
      xa0 += wih[0][jj] * xvj; xa1 += wih[1][jj] * xvj;
      xa2 += wih[2][jj] * xvj; xa3 += wih[3][jj] * xvj;
      const float hv = h_lds[(jj << 6) + l];
      ha0 += whh[0][jj] * hv; ha1 += whh[1][jj] * hv;
      ha2 += whh[2][jj] * hv; ha3 += whh[3][jj] * hv;
    }
    float g0 = xa0 + ha0, g1 = xa1 + ha1, g2 = xa2 + ha2, g3 = xa3 + ha3;
#pragma unroll
    for (int m = 1; m < 64; m <<= 1) {
      g0 += __shfl_xor(g0, m); g1 += __shfl_xor(g1, m);
      g2 += __shfl_xor(g2, m); g3 += __shfl_xor(g3, m);
    }
    if (l == 0) {
      g_lds[(wv << 2) + 0] = g0 + bias[0];
      g_lds[(wv << 2) + 1] = g1 + bias[1];
      g_lds[(wv << 2) + 2] = g2 + bias[2];
      g_lds[(wv << 2) + 3] = g3 + bias[3];
    }
    __syncthreads();
    if (tid < 4) {                       // torch gate order: i,f,g,o
      const int j = tid;
      const float ig = g_lds[0 + j], fg = g_lds[4 + j], gg = g_lds[8 + j], og = g_lds[12 + j];
      const float si = 1.f / (1.f + __expf(-ig));
      const float sf = 1.f / (1.f + __expf(-fg));
      const float so = 1.f / (1.f + __expf(-og));
      const float c  = sf * c_lds[j] + si * tanhf(gg);
      const float h  = so * tanhf(c);
      c_lds[j] = c;
      const int wd = s & (WW - 1);
      float e = enc_lds[j] + aw_lds[wd] * h;          // enc = aw @ hs (online)
      u64* dst = hbuf64 + ((size_t)((s + 1) & 1) << 10);
      astore(&dst[u0 + j], pack(h, (unsigned)(s + 1)));
      if (wd == WW - 1) {
        astore(&encs64[((size_t)(s >> 7) << 10) + u0 + j], pack(e, (unsigned)((s >> 7) + 1)));
        e = 0.f;
      }
      enc_lds[j] = e;
    }
    // no trailing barrier needed: next spin can only succeed after this WG's
    // tid<4 tagged stores, which happen after every wave passed the g_lds barrier
  }

  // ======================= layer 2: 64 sentence steps =======================
#pragma unroll
  for (int i = 0; i < 4; ++i) {          // reuse the same VGPRs for layer-2 weights
    const int row = (wv << 10) + u0 + i;
    bias[i] = bih2[row] + bhh2[row];
    const float* pih = Wih2 + (size_t)row * 1024 + l;
    const float* phh = Whh2 + (size_t)row * 1024 + l;
#pragma unroll
    for (int jj = 0; jj < 16; ++jj) {
      wih[i][jj] = pih[jj * 64];
      whh[i][jj] = phh[jj * 64];
    }
  }
#pragma unroll
  for (int i = 0; i < 4; ++i)
#pragma unroll
    for (int jj = 0; jj < 16; ++jj) {
      asm volatile("" : "+v"(wih[i][jj]));
      asm volatile("" : "+v"(whh[i][jj]));
    }
  if (tid < 4) c_lds[tid] = c2_0[u0 + tid];

  for (int s2 = 0; s2 < SS; ++s2) {
    const unsigned hs = (unsigned)(T1 + s2);
    // h first (this spin is the ordering gate for the whole iteration);
    // s2==0 spins for tag 8192 to close the layer-boundary overwrite hazard,
    // then overwrites with the true initial h2.
    const u64* hsrc = hbuf64 + ((size_t)(hs & 1) << 10);
    SPIN_STAGE(hsrc, hs, h_lds);
    // enc row for this sentence (tag written during layer 1)
    SPIN_STAGE(encs64 + ((size_t)s2 << 10), (unsigned)(s2 + 1), e_lds);
    if (s2 == 0) {
#pragma unroll
      for (int q = 0; q < 4; ++q) h_lds[(q << 8) + tid] = h2_0[(q << 8) + tid];
    }
    __syncthreads();

    float xa0 = 0.f, xa1 = 0.f, xa2 = 0.f, xa3 = 0.f;
    float ha0 = 0.f, ha1 = 0.f, ha2 = 0.f, ha3 = 0.f;
#pragma unroll
    for (int jj = 0; jj < 16; ++jj) {
      const float ev = e_lds[(jj << 6) + l];
      xa0 += wih[0][jj] * ev; xa1 += wih[1][jj] * ev;
      xa2 += wih[2][jj] * ev; xa3 += wih[3][jj] * ev;
      const float hv = h_lds[(jj << 6) + l];
      ha0 += whh[0][jj] * hv; ha1 += whh[1][jj] * hv;
      ha2 += whh[2][jj] * hv; ha3 += whh[3][jj] * hv;
    }
    float g0 = xa0 + ha0, g1 = xa1 + ha1, g2 = xa2 + ha2, g3 = xa3 + ha3;
#pragma unroll
    for (int m = 1; m < 64; m <<= 1) {
      g0 += __shfl_xor(g0, m); g1 += __shfl_xor(g1, m);
      g2 += __shfl_xor(g2, m); g3 += __shfl_xor(g3, m);
    }
    if (l == 0) {
      g_lds[(wv << 2) + 0] = g0 + bias[0];
      g_lds[(wv << 2) + 1] = g1 + bias[1];
      g_lds[(wv << 2) + 2] = g2 + bias[2];
      g_lds[(wv << 2) + 3] = g3 + bias[3];
    }
    __syncthreads();
    if (tid < 4) {
      const int j = tid;
      const float ig = g_lds[0 + j], fg = g_lds[4 + j], gg = g_lds[8 + j], og = g_lds[12 + j];
      const float si = 1.f / (1.f + __expf(-ig));
      const float sf = 1.f / (1.f + __expf(-fg));
      const float so = 1.f / (1.f + __expf(-og));
      const float c  = sf * c_lds[j] + si * tanhf(gg);
      const float h  = so * tanhf(c);
      c_lds[j] = c;
      row_lds[j] += as_lds[s2] * h;                    // row = asn @ hs2 (online)
      u64* dst = hbuf64 + ((size_t)((hs + 1) & 1) << 10);
      astore(&dst[u0 + j], pack(h, hs + 1));
    }
    __syncthreads();  // e_lds/h_lds deposits at s2+1 are NOT gated (enc tags are
                      // old) — barrier protects this iteration's LDS reads
  }

  // =================== final projection + sigmoid ===================
  if (tid == 0) {
    const float p = row_lds[0] * Wf[u0 + 0] + row_lds[1] * Wf[u0 + 1]
                  + row_lds[2] * Wf[u0 + 2] + row_lds[3] * Wf[u0 + 3];
    astore(&part64[wid], pack(p, 1u));
  }
  if (wid == 0) {
    u64 a;
    for (;;) { a = aload(&part64[tid]); if ((unsigned)(a >> 32) == 1u) break; }
    h_lds[tid] = __uint_as_float((unsigned)a);
    __syncthreads();
    if (wv == 0) {
      float p = h_lds[l] + h_lds[64 + l] + h_lds[128 + l] + h_lds[192 + l];
#pragma unroll
      for (int m = 1; m < 64; m <<= 1) p += __shfl_xor(p, m);
      if (l == 0) out[0] = 1.f / (1.f + __expf(-(p + bfb[0])));
    }
  }
}

extern "C" void kernel_launch(void* const* d_in, const int* in_sizes, int n_in,
                              void* d_out, int out_size, void* d_ws, size_t ws_size,
                              hipStream_t stream) {
  (void)in_sizes; (void)n_in; (void)out_size; (void)ws_size;
  const float* xin  = (const float*)d_in[0];
  const float* h1   = (const float*)d_in[1];
  const float* c1   = (const float*)d_in[2];
  const float* h2   = (const float*)d_in[3];
  const float* c2   = (const float*)d_in[4];
  const float* Wih1 = (const float*)d_in[5];
  const float* Whh1 = (const float*)d_in[6];
  const float* bih1 = (const float*)d_in[7];
  const float* bhh1 = (const float*)d_in[8];
  const float* Wih2 = (const float*)d_in[9];
  const float* Whh2 = (const float*)d_in[10];
  const float* bih2 = (const float*)d_in[11];
  const float* bhh2 = (const float*)d_in[12];
  const float* attw = (const float*)d_in[13];
  const float* atts = (const float*)d_in[14];
  const float* Wf   = (const float*)d_in[15];
  const float* bfb  = (const float*)d_in[16];

  u64* hbuf64 = (u64*)d_ws;                 // 2048 u64
  u64* encs64 = hbuf64 + 2048;              // 65536 u64
  u64* part64 = encs64 + 65536;             // 256 u64
  float* out  = (float*)d_out;

  // tags must start invalid (0) every call — replay-safe, graph-capture legal
  hipMemsetAsync(d_ws, 0, (2048 + 65536 + 256) * sizeof(u64), stream);
  lstm_hier_attn<<<dim3(NWG), dim3(NTH), 0, stream>>>(
      xin, h1, c1, h2, c2, Wih1, Whh1, bih1, bhh1,
      Wih2, Whh2, bih2, bhh2, attw, atts, Wf, bfb,
      hbuf64, encs64, part64, out);
}